// Round 1
// baseline (17.134 us; speedup 1.0000x reference)
//
#include <hip/hip_runtime.h>

// ChannelEstimator: per-pilot complex LS division + endpoint extrapolation +
// trainable linear interpolation over all Nfft subcarriers, fused in 1 kernel.
//
// Block = 256 threads handles CHUNK = 4096 subcarriers = 256 pilot segments.
// Phase 1: pilot LS -> LDS (257 entries, incl. boundary / extrapolated end).
// Phase 2: 16 coalesced float2 outputs per thread.

constexpr int NT    = 256;
constexpr int ITEMS = 16;
constexpr int CHUNK = NT * ITEMS;   // 4096 subcarriers per block

__global__ __launch_bounds__(NT) void ce_kernel(
    const float* __restrict__ Y_real, const float* __restrict__ Y_imag,
    const float* __restrict__ Xp_real, const float* __restrict__ Xp_imag,
    const float* __restrict__ weights,
    const float* __restrict__ alpha_p, const float* __restrict__ beta_p,
    const float* __restrict__ gamma_p,
    const int* __restrict__ pilot_pos,
    float2* __restrict__ out, int Nfft, int P)
{
    __shared__ float sHr [NT + 1];
    __shared__ float sHi [NT + 1];
    __shared__ float sLoc[NT + 1];
    __shared__ float sInv[NT + 1];

    const int t    = threadIdx.x;
    const int p0   = blockIdx.x * NT;      // first pilot index of this block
    const int base = blockIdx.x * CHUNK;   // first subcarrier of this block

    // weighted LS estimate at pilot k: H = (Y[pos] / Xp[k]) * w[k]
    auto ls = [&](int k, float& hr, float& hi) {
        int   pos = pilot_pos[k];
        float yr = Y_real[pos], yi = Y_imag[pos];
        float xr = Xp_real[k],  xi = Xp_imag[k];
        float inv = 1.0f / (xr * xr + xi * xi);
        float wk  = weights[k];
        hr = (yr * xr + yi * xi) * inv * wk;
        hi = (yi * xr - yr * xi) * inv * wk;
    };

    // ---- phase 1: pilots p0 .. p0+NT into LDS ----
    {
        int k = p0 + t;
        if (k < P) {
            float hr, hi; ls(k, hr, hi);
            sHr[t] = hr; sHi[t] = hi;
            sLoc[t] = (float)pilot_pos[k];
        }
    }
    if (t == 0) {
        int ke = p0 + NT;
        if (ke < P) {
            float hr, hi; ls(ke, hr, hi);
            sHr[NT] = hr; sHi[NT] = hi;
            sLoc[NT] = (float)pilot_pos[ke];
        } else {
            // extended endpoint at Nfft-1: linear extrapolation from last two pilots
            float hr1, hi1, hr2, hi2;
            ls(P - 1, hr1, hi1);
            ls(P - 2, hr2, hi2);
            float l1 = (float)pilot_pos[P - 1];
            float l2 = (float)pilot_pos[P - 2];
            float inv_dx = 1.0f / (l1 - l2);
            float dend   = (float)(Nfft - 1) - l1;
            sHr[NT] = hr1 + (hr1 - hr2) * inv_dx * dend;
            sHi[NT] = hi1 + (hi1 - hi2) * inv_dx * dend;
            sLoc[NT] = (float)(Nfft - 1);
        }
    }
    __syncthreads();

    // ---- phase 1.5: per-segment reciprocal width (avoids 4M divides) ----
    {
        float d = sLoc[t + 1] - sLoc[t];
        sInv[t] = (d > 0.0f) ? (1.0f / d) : 0.0f;   // matches jnp.where(X1-X0>0,...)
    }
    __syncthreads();

    const float a = *alpha_p;
    const float b = *beta_p;
    const float g = *gamma_p;

    // ---- phase 2: interpolate, coalesced float2 stores ----
    #pragma unroll
    for (int j = 0; j < ITEMS; ++j) {
        int i = base + j * NT + t;
        if (i >= Nfft) break;
        int lp = (i >> 4) - p0;               // segment index within block (spacing-16 grid)
        float X0  = sLoc[lp];
        float df  = ((float)i - X0) * sInv[lp];
        float hr0 = sHr[lp], hr1 = sHr[lp + 1];
        float hi0 = sHi[lp], hi1 = sHi[lp + 1];
        float2 o;
        o.x = a * hr1 + b * hr0 + g * df;
        o.y = a * hi1 + b * hi0;
        out[i] = o;
    }
}

extern "C" void kernel_launch(void* const* d_in, const int* in_sizes, int n_in,
                              void* d_out, int out_size, void* d_ws, size_t ws_size,
                              hipStream_t stream) {
    const float* Yr = (const float*)d_in[0];
    const float* Yi = (const float*)d_in[1];
    const float* Xr = (const float*)d_in[2];
    const float* Xi = (const float*)d_in[3];
    const float* w  = (const float*)d_in[4];
    const float* al = (const float*)d_in[5];
    const float* be = (const float*)d_in[6];
    const float* ga = (const float*)d_in[7];
    const int*   pp = (const int*)d_in[8];
    const int Nfft = in_sizes[0];   // 4194304
    const int P    = in_sizes[2];   // 262144

    const int grid = (Nfft + CHUNK - 1) / CHUNK;   // 1024 blocks
    ce_kernel<<<grid, NT, 0, stream>>>(Yr, Yi, Xr, Xi, w, al, be, ga, pp,
                                       (float2*)d_out, Nfft, P);
}

// Round 3
// 15.525 us; speedup vs baseline: 1.1036x; 1.1036x over previous
//
#include <hip/hip_runtime.h>

// ChannelEstimator: per-pilot complex LS division + endpoint extrapolation +
// trainable linear interpolation over all Nfft subcarriers, fused in 1 kernel.
//
// Block = 128 threads handles CHUNK = 2048 subcarriers = 128 pilot segments.
// Phase 1: pilot LS -> LDS (129 entries, incl. boundary / extrapolated end).
// Phase 2: 8 iterations x float4 nontemporal store (2 subcarriers per lane).
// Since the pair (i0 even, i0+1) never crosses a spacing-16 boundary, both
// subcarriers of a float4 share one pilot segment.

typedef float f32x4 __attribute__((ext_vector_type(4)));  // native vec for nontemporal builtin

constexpr int NT    = 128;
constexpr int PAIRS = 8;                // float4 iterations per thread
constexpr int CHUNK = NT * PAIRS * 2;   // 2048 subcarriers per block

__global__ __launch_bounds__(NT) void ce_kernel(
    const float* __restrict__ Y_real, const float* __restrict__ Y_imag,
    const float* __restrict__ Xp_real, const float* __restrict__ Xp_imag,
    const float* __restrict__ weights,
    const float* __restrict__ alpha_p, const float* __restrict__ beta_p,
    const float* __restrict__ gamma_p,
    const int* __restrict__ pilot_pos,
    f32x4* __restrict__ out4, int Nfft, int P)
{
    constexpr int NP = CHUNK / 16;   // pilots per block = 128 == NT
    __shared__ float sHr [NP + 1];
    __shared__ float sHi [NP + 1];
    __shared__ float sLoc[NP + 1];
    __shared__ float sInv[NP + 1];

    const int t    = threadIdx.x;
    const int p0   = blockIdx.x * NP;      // first pilot index of this block
    const int base = blockIdx.x * CHUNK;   // first subcarrier of this block

    // weighted LS estimate at pilot k: H = (Y[pos] / Xp[k]) * w[k]
    auto ls = [&](int k, float& hr, float& hi) {
        int   pos = pilot_pos[k];
        float yr = Y_real[pos], yi = Y_imag[pos];
        float xr = Xp_real[k],  xi = Xp_imag[k];
        float inv = 1.0f / (xr * xr + xi * xi);
        float wk  = weights[k];
        hr = (yr * xr + yi * xi) * inv * wk;
        hi = (yi * xr - yr * xi) * inv * wk;
    };

    // ---- phase 1: pilots p0 .. p0+NP into LDS ----
    {
        int k = p0 + t;
        if (k < P) {
            float hr, hi; ls(k, hr, hi);
            sHr[t] = hr; sHi[t] = hi;
            sLoc[t] = (float)pilot_pos[k];
        }
    }
    if (t == 0) {
        int ke = p0 + NP;
        if (ke < P) {
            float hr, hi; ls(ke, hr, hi);
            sHr[NP] = hr; sHi[NP] = hi;
            sLoc[NP] = (float)pilot_pos[ke];
        } else {
            // extended endpoint at Nfft-1: linear extrapolation from last two pilots
            float hr1, hi1, hr2, hi2;
            ls(P - 1, hr1, hi1);
            ls(P - 2, hr2, hi2);
            float l1 = (float)pilot_pos[P - 1];
            float l2 = (float)pilot_pos[P - 2];
            float inv_dx = 1.0f / (l1 - l2);
            float dend   = (float)(Nfft - 1) - l1;
            sHr[NP] = hr1 + (hr1 - hr2) * inv_dx * dend;
            sHi[NP] = hi1 + (hi1 - hi2) * inv_dx * dend;
            sLoc[NP] = (float)(Nfft - 1);
        }
    }
    __syncthreads();

    // ---- phase 1.5: per-segment reciprocal width (avoids per-subcarrier divides) ----
    {
        float d = sLoc[t + 1] - sLoc[t];
        sInv[t] = (d > 0.0f) ? (1.0f / d) : 0.0f;   // matches jnp.where(X1-X0>0,...)
    }
    __syncthreads();

    const float a = *alpha_p;
    const float b = *beta_p;
    const float g = *gamma_p;

    // ---- phase 2: interpolate, 2 subcarriers per float4 nontemporal store ----
    #pragma unroll
    for (int j = 0; j < PAIRS; ++j) {
        int i0 = base + j * (NT * 2) + 2 * t;     // even
        if (i0 >= Nfft) break;
        int lp = (i0 >> 4) - p0;                  // shared by i0 and i0+1
        float X0  = sLoc[lp];
        float inv = sInv[lp];
        float df0 = ((float)i0 - X0) * inv;
        float hr0 = sHr[lp], hr1 = sHr[lp + 1];
        float hi0 = sHi[lp], hi1 = sHi[lp + 1];
        float rr = a * hr1 + b * hr0;
        float ii = a * hi1 + b * hi0;
        f32x4 o;
        o.x = rr + g * df0;
        o.y = ii;
        o.z = rr + g * (df0 + inv);
        o.w = ii;
        __builtin_nontemporal_store(o, &out4[(base >> 1) + j * NT + t]);
    }
}

extern "C" void kernel_launch(void* const* d_in, const int* in_sizes, int n_in,
                              void* d_out, int out_size, void* d_ws, size_t ws_size,
                              hipStream_t stream) {
    const float* Yr = (const float*)d_in[0];
    const float* Yi = (const float*)d_in[1];
    const float* Xr = (const float*)d_in[2];
    const float* Xi = (const float*)d_in[3];
    const float* w  = (const float*)d_in[4];
    const float* al = (const float*)d_in[5];
    const float* be = (const float*)d_in[6];
    const float* ga = (const float*)d_in[7];
    const int*   pp = (const int*)d_in[8];
    const int Nfft = in_sizes[0];   // 4194304
    const int P    = in_sizes[2];   // 262144

    const int grid = (Nfft + CHUNK - 1) / CHUNK;   // 2048 blocks
    ce_kernel<<<grid, NT, 0, stream>>>(Yr, Yi, Xr, Xi, w, al, be, ga, pp,
                                       (f32x4*)d_out, Nfft, P);
}